// Round 7
// baseline (518.835 us; speedup 1.0000x reference)
//
#include <hip/hip_runtime.h>
#include <hip/hip_bf16.h>

#define B 8
#define C 192
#define OC 576
#define H 128
#define W 128
#define N (H*W)          // 16384
#define HEADS 4
#define CH 48            // C / HEADS

typedef __attribute__((ext_vector_type(8))) short short8;
typedef __attribute__((ext_vector_type(4))) float floatx4;

__device__ __forceinline__ float bf2f(unsigned short u) {
    union { unsigned int i; float f; } v; v.i = ((unsigned int)u) << 16; return v.f;
}
__device__ __forceinline__ unsigned short f2bf(float f) {
    __hip_bfloat16 h = (__hip_bfloat16)f;
    unsigned short u; __builtin_memcpy(&u, &h, 2); return u;
}

// ---------------------------------------------------------------------------
// K0: zero atomically-accumulated scratch
// ---------------------------------------------------------------------------
__global__ void k_zero(float* __restrict__ normsq, float* __restrict__ G) {
    int i = blockIdx.x * 256 + threadIdx.x;
    if (i < B * 2 * C) normsq[i] = 0.0f;
    if (i < B * HEADS * CH * CH) G[i] = 0.0f;
}

// ---------------------------------------------------------------------------
// K1 (fused): one pass over x+Input ->
//   mask_single[b][p] = sum_c cm_w[c]*((Input-x)>thr)
//   xt bf16 [b][n][c]  (transpose-convert of x)
// v7: 256-pixel tile, 1 px/thread. Per channel the BLOCK reads 1KB
// contiguous (8x longer DRAM bursts than the 32-px tiles, which were
// row-activation-bound at ~2.8 TB/s effective). Mask accumulator lives in
// one register per thread -> no partials/LDS/barriers. xt packed in groups
// of 8 channels -> uint4 stores (pk live regs = 4, loads pipeline freely).
// ---------------------------------------------------------------------------
__global__ __launch_bounds__(256) void k_mask_xt(
    const float* __restrict__ x, const float* __restrict__ inp,
    const float* __restrict__ cm_w, const float* __restrict__ thr,
    float* __restrict__ mask_single, unsigned short* __restrict__ xt) {
    __shared__ float cw[C];
    int tid = threadIdx.x;
    if (tid < C) cw[tid] = cm_w[tid];
    __syncthreads();
    int b = blockIdx.y, n0 = blockIdx.x * 256;
    float th = thr[0];
    const float* xb = x + (size_t)b * C * N + n0 + tid;
    const float* ib = inp + (size_t)b * C * N + n0 + tid;
    unsigned short* db = xt + ((size_t)b * N + n0 + tid) * C;
    float macc = 0.f;
    #pragma unroll
    for (int j = 0; j < C / 8; ++j) {          // 24 groups of 8 channels
        unsigned int pk[4];
        #pragma unroll
        for (int jj = 0; jj < 4; ++jj) {
            int c = j * 8 + jj * 2;
            float x0 = xb[(size_t)c * N];
            float x1 = xb[(size_t)(c + 1) * N];
            float i0 = ib[(size_t)c * N];
            float i1 = ib[(size_t)(c + 1) * N];
            macc += ((i0 - x0) > th) ? cw[c] : 0.f;
            macc += ((i1 - x1) > th) ? cw[c + 1] : 0.f;
            pk[jj] = (unsigned int)f2bf(x0) | ((unsigned int)f2bf(x1) << 16);
        }
        *(uint4*)&db[j * 8] = *(uint4*)&pk[0];
    }
    mask_single[(size_t)b * N + n0 + tid] = macc;
}

// ---------------------------------------------------------------------------
// K3: qkv 1x1 conv via MFMA bf16: qkv_raw[b][o][n] = sum_c w[o][c]*x[b][c][n]
// ---------------------------------------------------------------------------
#define PAD 40
__global__ __launch_bounds__(256) void k_qkv_mfma(
    const unsigned short* __restrict__ xt, const float* __restrict__ w,
    unsigned short* __restrict__ out) {
    __shared__ __align__(16) unsigned short As[64][PAD];
    __shared__ __align__(16) unsigned short Bs[256][PAD];
    int b = blockIdx.z, m0 = blockIdx.y * 64, n0 = blockIdx.x * 256;
    int tid = threadIdx.x, wave = tid >> 6, lane = tid & 63;
    int l15 = lane & 15, quad = lane >> 4;
    floatx4 acc[4][4];
    #pragma unroll
    for (int i = 0; i < 4; ++i)
        #pragma unroll
        for (int j = 0; j < 4; ++j) acc[i][j] = (floatx4){0.f, 0.f, 0.f, 0.f};
    const unsigned short* xb = xt + (size_t)b * N * C;
    for (int k0 = 0; k0 < C; k0 += 32) {
        {
            int m = tid >> 2, ko = tid & 3;
            const float* wr = w + (size_t)(m0 + m) * C + k0 + ko * 8;
            float4 f0 = *(const float4*)&wr[0];
            float4 f1 = *(const float4*)&wr[4];
            unsigned int* dp = (unsigned int*)&As[m][ko * 8];
            dp[0] = (unsigned int)f2bf(f0.x) | ((unsigned int)f2bf(f0.y) << 16);
            dp[1] = (unsigned int)f2bf(f0.z) | ((unsigned int)f2bf(f0.w) << 16);
            dp[2] = (unsigned int)f2bf(f1.x) | ((unsigned int)f2bf(f1.y) << 16);
            dp[3] = (unsigned int)f2bf(f1.z) | ((unsigned int)f2bf(f1.w) << 16);
        }
        #pragma unroll
        for (int t = 0; t < 4; ++t) {
            int i = tid + t * 256;
            int n = i >> 2, ko = i & 3;
            *(uint4*)&Bs[n][ko * 8] = *(const uint4*)&xb[(size_t)(n0 + n) * C + k0 + ko * 8];
        }
        __syncthreads();
        short8 af[4], bf[4];
        #pragma unroll
        for (int mt = 0; mt < 4; ++mt)
            af[mt] = *(const short8*)&As[mt * 16 + l15][quad * 8];
        #pragma unroll
        for (int nt = 0; nt < 4; ++nt)
            bf[nt] = *(const short8*)&Bs[wave * 64 + nt * 16 + l15][quad * 8];
        #pragma unroll
        for (int mt = 0; mt < 4; ++mt)
            #pragma unroll
            for (int nt = 0; nt < 4; ++nt)
                acc[mt][nt] = __builtin_amdgcn_mfma_f32_16x16x32_bf16(
                    af[mt], bf[nt], acc[mt][nt], 0, 0, 0);
        __syncthreads();
    }
    unsigned short* ob = out + (size_t)b * OC * N;
    #pragma unroll
    for (int mt = 0; mt < 4; ++mt)
        #pragma unroll
        for (int r = 0; r < 4; ++r) {
            int o = m0 + mt * 16 + quad * 4 + r;
            #pragma unroll
            for (int nt = 0; nt < 4; ++nt)
                ob[(size_t)o * N + n0 + wave * 64 + nt * 16 + l15] =
                    f2bf(acc[mt][nt][r]);
        }
}

// ---------------------------------------------------------------------------
// K4: depthwise 3x3 (LDS-tiled) + mask + normsq.  v3:
//   - staging uint4 (8 bf16) per unit
//   - 2 output columns per thread, LDS tile [34][132]
// ---------------------------------------------------------------------------
__global__ __launch_bounds__(256) void k_dwconv(
    const unsigned short* __restrict__ qkv_raw, const float* __restrict__ dw_w,
    const float* __restrict__ mask_single, unsigned short* __restrict__ qk_out,
    unsigned short* __restrict__ v_out, float* __restrict__ normsq) {
    __shared__ float tile[34][132];
    __shared__ float red[4];
    int tid = threadIdx.x;
    int b = blockIdx.z, o = blockIdx.y;
    int y0 = blockIdx.x * 32;
    const unsigned short* in = qkv_raw + ((size_t)b * OC + o) * N;
    // staging: uint4 (8 bf16) per unit, 34 rows x 16 units
    for (int i = tid; i < 34 * 16; i += 256) {
        int r = i >> 4, dw = i & 15;
        int yy = y0 + r - 1;
        float4 f0 = {0.f, 0.f, 0.f, 0.f};
        float4 f1 = {0.f, 0.f, 0.f, 0.f};
        if (yy >= 0 && yy < H) {
            uint4 u = *(const uint4*)&in[yy * W + dw * 8];
            union { unsigned int i; float f; } a0, a1, a2, a3, a4, a5, a6, a7;
            a0.i = u.x << 16; a1.i = u.x & 0xffff0000u;
            a2.i = u.y << 16; a3.i = u.y & 0xffff0000u;
            a4.i = u.z << 16; a5.i = u.z & 0xffff0000u;
            a6.i = u.w << 16; a7.i = u.w & 0xffff0000u;
            f0.x = a0.f; f0.y = a1.f; f0.z = a2.f; f0.w = a3.f;
            f1.x = a4.f; f1.y = a5.f; f1.z = a6.f; f1.w = a7.f;
        }
        *(float4*)&tile[r][dw * 8] = f0;
        *(float4*)&tile[r][dw * 8 + 4] = f1;
        if (dw == 0)  { tile[r][130] = 0.f; tile[r][131] = 0.f; }
        if (dw == 15) { tile[r][128] = 0.f; }
    }
    __syncthreads();
    const float* wp = dw_w + o * 9;
    float w00 = wp[0], w01 = wp[1], w02 = wp[2];
    float w10 = wp[3], w11 = wp[4], w12 = wp[5];
    float w20 = wp[6], w21 = wp[7], w22 = wp[8];
    int c = tid & 63, g = tid >> 6;
    int col = c * 2;
    int lbase = (c == 0) ? 130 : (col - 2);   // .y of this pair = left neighbor
    bool is_qk = (o < 2 * C);
    float m_acc = 0.f;
    int rbase = g * 8;
    float2 p0l = *(const float2*)&tile[rbase][lbase];
    float2 p0m = *(const float2*)&tile[rbase][col];
    float2 p0r = *(const float2*)&tile[rbase][col + 2];
    float2 p1l = *(const float2*)&tile[rbase + 1][lbase];
    float2 p1m = *(const float2*)&tile[rbase + 1][col];
    float2 p1r = *(const float2*)&tile[rbase + 1][col + 2];
    unsigned short* qkb = qk_out + ((size_t)b * 2 * C + o) * N;
    unsigned short* vb  = v_out + ((size_t)b * C + (o - 2 * C)) * N;
    const float* mb = mask_single + (size_t)b * N;
    #pragma unroll
    for (int rl = 0; rl < 8; ++rl) {
        int tr = rbase + rl + 2;
        float2 p2l = *(const float2*)&tile[tr][lbase];
        float2 p2m = *(const float2*)&tile[tr][col];
        float2 p2r = *(const float2*)&tile[tr][col + 2];
        float sx = w00 * p0l.y + w01 * p0m.x + w02 * p0m.y
                 + w10 * p1l.y + w11 * p1m.x + w12 * p1m.y
                 + w20 * p2l.y + w21 * p2m.x + w22 * p2m.y;
        float sy = w00 * p0m.x + w01 * p0m.y + w02 * p0r.x
                 + w10 * p1m.x + w11 * p1m.y + w12 * p1r.x
                 + w20 * p2m.x + w21 * p2m.y + w22 * p2r.x;
        int p = (y0 + rbase + rl) * W + col;
        if (is_qk) {
            float2 mv = *(const float2*)&mb[p];
            sx *= mv.x; sy *= mv.y;
        }
        unsigned short hx = f2bf(sx), hy = f2bf(sy);
        unsigned int pk = (unsigned int)hx | ((unsigned int)hy << 16);
        if (is_qk) {
            *(unsigned int*)&qkb[p] = pk;
            float fx = bf2f(hx), fy = bf2f(hy);
            m_acc += fx * fx + fy * fy;
        } else {
            *(unsigned int*)&vb[p] = pk;
        }
        p0l = p1l; p0m = p1m; p0r = p1r;
        p1l = p2l; p1m = p2m; p1r = p2r;
    }
    if (is_qk) {
        #pragma unroll
        for (int off = 32; off > 0; off >>= 1) m_acc += __shfl_down(m_acc, off);
        if ((tid & 63) == 0) red[tid >> 6] = m_acc;
        __syncthreads();
        if (tid == 0)
            atomicAdd(&normsq[b * 2 * C + o], red[0] + red[1] + red[2] + red[3]);
    }
}

// ---------------------------------------------------------------------------
// K5: transpose v bf16 [b][c][n] -> v_t [b][n][c]
// ---------------------------------------------------------------------------
__global__ __launch_bounds__(256) void k_xpose_v(
    const unsigned short* __restrict__ src, unsigned short* __restrict__ dst) {
    __shared__ unsigned short t[64][C + 2];
    int tid = threadIdx.x;
    int b = blockIdx.y, n0 = blockIdx.x * 64;
    const unsigned short* sb = src + (size_t)b * C * N;
    for (int i = tid; i < C * 32; i += 256) {
        int c = i >> 5, np = i & 31;
        unsigned int u = *(const unsigned int*)&sb[(size_t)c * N + n0 + np * 2];
        t[np * 2][c] = (unsigned short)(u & 0xffffu);
        t[np * 2 + 1][c] = (unsigned short)(u >> 16);
    }
    __syncthreads();
    unsigned short* db = dst + ((size_t)b * N + n0) * C;
    for (int i = tid; i < 64 * (C / 8); i += 256) {
        int nn = i / (C / 8), ch = i % (C / 8);
        union { unsigned short h[8]; uint4 u; } pk;
        #pragma unroll
        for (int j = 0; j < 8; ++j) pk.h[j] = t[nn][ch * 8 + j];
        *(uint4*)&db[(size_t)nn * C + ch * 8] = pk.u;
    }
}

// ---------------------------------------------------------------------------
// K6: Gram via MFMA: G[b][h][i][j] = sum_n q[i][n]*k[j][n].
// ---------------------------------------------------------------------------
__global__ __launch_bounds__(256) void k_gram_mfma(
    const unsigned short* __restrict__ qk, float* __restrict__ G) {
    __shared__ float Gs[4][CH][CH];
    int tid = threadIdx.x, wave = tid >> 6, lane = tid & 63;
    int l15 = lane & 15, quad = lane >> 4;
    int b = blockIdx.z, hh = blockIdx.y;
    int nb = blockIdx.x * 512 + wave * 128;
    const unsigned short* qb = qk + ((size_t)b * 2 * C + hh * CH) * N;
    const unsigned short* kb = qb + (size_t)C * N;
    floatx4 acc[3][3];
    #pragma unroll
    for (int i = 0; i < 3; ++i)
        #pragma unroll
        for (int j = 0; j < 3; ++j) acc[i][j] = (floatx4){0.f, 0.f, 0.f, 0.f};
    #pragma unroll
    for (int ks = 0; ks < 4; ++ks) {
        int n_off = nb + ks * 32 + quad * 8;
        short8 af[3], bf[3];
        #pragma unroll
        for (int it = 0; it < 3; ++it)
            af[it] = *(const short8*)&qb[(size_t)(it * 16 + l15) * N + n_off];
        #pragma unroll
        for (int jt = 0; jt < 3; ++jt)
            bf[jt] = *(const short8*)&kb[(size_t)(jt * 16 + l15) * N + n_off];
        #pragma unroll
        for (int it = 0; it < 3; ++it)
            #pragma unroll
            for (int jt = 0; jt < 3; ++jt)
                acc[it][jt] = __builtin_amdgcn_mfma_f32_16x16x32_bf16(
                    af[it], bf[jt], acc[it][jt], 0, 0, 0);
    }
    #pragma unroll
    for (int it = 0; it < 3; ++it)
        #pragma unroll
        for (int jt = 0; jt < 3; ++jt)
            #pragma unroll
            for (int r = 0; r < 4; ++r)
                Gs[wave][it * 16 + quad * 4 + r][jt * 16 + l15] = acc[it][jt][r];
    __syncthreads();
    float* Gb = G + (size_t)(b * HEADS + hh) * CH * CH;
    for (int idx = tid; idx < CH * CH; idx += 256) {
        int i = idx / CH, j = idx % CH;
        atomicAdd(&Gb[idx], Gs[0][i][j] + Gs[1][i][j] + Gs[2][i][j] + Gs[3][i][j]);
    }
}

// ---------------------------------------------------------------------------
// K7: softmax(G*temp/(|q||k|)) folded into proj -> W_eff bf16 [b][o][c]
// ---------------------------------------------------------------------------
__global__ __launch_bounds__(256) void k_attn_weff(
    const float* __restrict__ G, const float* __restrict__ normsq,
    const float* __restrict__ temperature, const float* __restrict__ proj_w,
    unsigned short* __restrict__ W_eff) {
    int b = blockIdx.x;
    int o_base = blockIdx.y * 32;
    __shared__ float attn[HEADS][CH][CH];
    __shared__ float inv_n[2 * C];
    int tid = threadIdx.x;
    for (int l = tid; l < 2 * C; l += 256)
        inv_n[l] = 1.0f / fmaxf(sqrtf(normsq[b * 2 * C + l]), 1e-12f);
    __syncthreads();
    if (tid < HEADS * CH) {
        int hh = tid / CH, i = tid % CH;
        float iq = inv_n[hh * CH + i] * temperature[hh];
        const float* Gr = G + ((size_t)(b * HEADS + hh) * CH + i) * CH;
        float mx = -1e30f;
        for (int j = 0; j < CH; ++j) {
            float l2 = Gr[j] * iq * inv_n[C + hh * CH + j];
            attn[hh][i][j] = l2;
            mx = fmaxf(mx, l2);
        }
        float sm = 0.0f;
        for (int j = 0; j < CH; ++j) {
            float e = expf(attn[hh][i][j] - mx);
            attn[hh][i][j] = e;
            sm += e;
        }
        float is = 1.0f / sm;
        for (int j = 0; j < CH; ++j) attn[hh][i][j] *= is;
    }
    __syncthreads();
    for (int idx = tid; idx < 32 * C; idx += 256) {
        int o = o_base + idx / C, cp = idx % C;
        int hh = cp / CH, j = cp % CH;
        const float* pw = proj_w + (size_t)o * C + hh * CH;
        float s = 0.0f;
        #pragma unroll 8
        for (int i = 0; i < CH; ++i) s += pw[i] * attn[hh][i][j];
        W_eff[((size_t)b * C + o) * C + cp] = f2bf(s);
    }
}

// ---------------------------------------------------------------------------
// K8: out = W_eff[b] (192x192) @ v_t^T -> fp32, MFMA. Tile 64m x 256n.
// ---------------------------------------------------------------------------
__global__ __launch_bounds__(256) void k_out_mfma(
    const unsigned short* __restrict__ vt, const unsigned short* __restrict__ W_eff,
    float* __restrict__ out) {
    __shared__ __align__(16) unsigned short As[64][PAD];
    __shared__ __align__(16) unsigned short Bs[256][PAD];
    int b = blockIdx.z, m0 = blockIdx.y * 64, n0 = blockIdx.x * 256;
    int tid = threadIdx.x, wave = tid >> 6, lane = tid & 63;
    int l15 = lane & 15, quad = lane >> 4;
    floatx4 acc[4][4];
    #pragma unroll
    for (int i = 0; i < 4; ++i)
        #pragma unroll
        for (int j = 0; j < 4; ++j) acc[i][j] = (floatx4){0.f, 0.f, 0.f, 0.f};
    const unsigned short* vb = vt + (size_t)b * N * C;
    const unsigned short* wb = W_eff + (size_t)b * C * C;
    for (int k0 = 0; k0 < C; k0 += 32) {
        {
            int m = tid >> 2, ko = tid & 3;
            *(uint4*)&As[m][ko * 8] = *(const uint4*)&wb[(size_t)(m0 + m) * C + k0 + ko * 8];
        }
        #pragma unroll
        for (int t = 0; t < 4; ++t) {
            int i = tid + t * 256;
            int n = i >> 2, ko = i & 3;
            *(uint4*)&Bs[n][ko * 8] = *(const uint4*)&vb[(size_t)(n0 + n) * C + k0 + ko * 8];
        }
        __syncthreads();
        short8 af[4], bf[4];
        #pragma unroll
        for (int mt = 0; mt < 4; ++mt)
            af[mt] = *(const short8*)&As[mt * 16 + l15][quad * 8];
        #pragma unroll
        for (int nt = 0; nt < 4; ++nt)
            bf[nt] = *(const short8*)&Bs[wave * 64 + nt * 16 + l15][quad * 8];
        #pragma unroll
        for (int mt = 0; mt < 4; ++mt)
            #pragma unroll
            for (int nt = 0; nt < 4; ++nt)
                acc[mt][nt] = __builtin_amdgcn_mfma_f32_16x16x32_bf16(
                    af[mt], bf[nt], acc[mt][nt], 0, 0, 0);
        __syncthreads();
    }
    float* ob = out + (size_t)b * C * N;
    #pragma unroll
    for (int mt = 0; mt < 4; ++mt)
        #pragma unroll
        for (int r = 0; r < 4; ++r) {
            int o = m0 + mt * 16 + quad * 4 + r;
            #pragma unroll
            for (int nt = 0; nt < 4; ++nt)
                ob[(size_t)o * N + n0 + wave * 64 + nt * 16 + l15] = acc[mt][nt][r];
        }
}

// ---------------------------------------------------------------------------
extern "C" void kernel_launch(void* const* d_in, const int* in_sizes, int n_in,
                              void* d_out, int out_size, void* d_ws, size_t ws_size,
                              hipStream_t stream) {
    const float* x           = (const float*)d_in[0];
    const float* inp         = (const float*)d_in[1];
    const float* qkv_w       = (const float*)d_in[2];
    const float* dw_w        = (const float*)d_in[3];
    const float* proj_w      = (const float*)d_in[4];
    const float* cm_w        = (const float*)d_in[5];
    const float* temperature = (const float*)d_in[6];
    const float* threshold   = (const float*)d_in[7];
    float* out = (float*)d_out;

    char* ws = (char*)d_ws;
    const size_t SZ_RAW = (size_t)B * OC * N * 2;      // 150,994,944
    const size_t SZ_QK  = (size_t)B * 2 * C * N * 2;   // 100,663,296
    const size_t SZ_XT  = (size_t)B * N * C * 2;       //  50,331,648
    unsigned short* qkv_raw = (unsigned short*)ws;
    unsigned short* v_t     = (unsigned short*)ws;                       // reuse
    unsigned short* qk      = (unsigned short*)(ws + SZ_RAW);
    unsigned short* xt      = (unsigned short*)(ws + SZ_RAW + SZ_QK);
    unsigned short* vbuf    = xt;                                        // reuse
    char* tail = ws + SZ_RAW + SZ_QK + SZ_XT;
    float* mask_single = (float*)tail;
    float* normsq = (float*)(tail + (size_t)B * N * 4);
    float* G = normsq + B * 2 * C;
    unsigned short* W_eff = (unsigned short*)(G + B * HEADS * CH * CH);

    k_zero<<<dim3((B * HEADS * CH * CH + 255) / 256), 256, 0, stream>>>(normsq, G);
    k_mask_xt<<<dim3(N / 256, B), 256, 0, stream>>>(x, inp, cm_w, threshold, mask_single, xt);
    k_qkv_mfma<<<dim3(N / 256, OC / 64, B), 256, 0, stream>>>(xt, qkv_w, qkv_raw);
    k_dwconv<<<dim3(H / 32, OC, B), 256, 0, stream>>>(qkv_raw, dw_w, mask_single, qk, vbuf, normsq);
    k_xpose_v<<<dim3(N / 64, B), 256, 0, stream>>>(vbuf, v_t);
    k_gram_mfma<<<dim3(N / 512, HEADS, B), 256, 0, stream>>>(qk, G);
    k_attn_weff<<<dim3(B, 6), 256, 0, stream>>>(G, normsq, temperature, proj_w, W_eff);
    k_out_mfma<<<dim3(N / 256, C / 64, B), 256, 0, stream>>>(v_t, W_eff, out);
}

// Round 9
// 504.050 us; speedup vs baseline: 1.0293x; 1.0293x over previous
//
#include <hip/hip_runtime.h>
#include <hip/hip_bf16.h>

#define B 8
#define C 192
#define OC 576
#define H 128
#define W 128
#define N (H*W)          // 16384
#define HEADS 4
#define CH 48            // C / HEADS

typedef __attribute__((ext_vector_type(8))) short short8;
typedef __attribute__((ext_vector_type(4))) float floatx4;

__device__ __forceinline__ float bf2f(unsigned short u) {
    union { unsigned int i; float f; } v; v.i = ((unsigned int)u) << 16; return v.f;
}
__device__ __forceinline__ unsigned short f2bf(float f) {
    __hip_bfloat16 h = (__hip_bfloat16)f;
    unsigned short u; __builtin_memcpy(&u, &h, 2); return u;
}

// ---------------------------------------------------------------------------
// K0: zero atomically-accumulated scratch (now also mask_single)
// ---------------------------------------------------------------------------
__global__ void k_zero(float* __restrict__ normsq, float* __restrict__ G,
                       float* __restrict__ mask_single) {
    int i = blockIdx.x * 256 + threadIdx.x;
    if (i < B * 2 * C) normsq[i] = 0.0f;
    if (i < B * HEADS * CH * CH) G[i] = 0.0f;
    if (i < B * N) mask_single[i] = 0.0f;
}

// ---------------------------------------------------------------------------
// K1 (fused): one pass over x+Input ->
//   mask_single[b][p] += sum_{c in half} cm_w[c]*((Input-x)>thr)  (atomic)
//   xt bf16 [b][n][c]  (transpose-convert of x)
// v8: 256-px tile, channel-split 2. Every wave read instruction is
// 64 lanes x float4 = 1KB CONTIGUOUS (previous variants were 128-256B
// segments -> DRAM page-activation bound at ~2.8 TB/s effective).
// Wave w handles 12 channel-pairs; bf16 pairs packed u32 into ts[256][49];
// flush writes full contiguous 192B half-rows (complementary half written
// by the adjacent blockIdx.y -> L2 merges the shared cacheline).
// ---------------------------------------------------------------------------
__global__ __launch_bounds__(256) void k_mask_xt(
    const float* __restrict__ x, const float* __restrict__ inp,
    const float* __restrict__ cm_w, const float* __restrict__ thr,
    float* __restrict__ mask_single, unsigned short* __restrict__ xt) {
    __shared__ unsigned int ts[256][49];   // [px][channel-pair] packed bf16x2
    __shared__ float partials[4][256];
    int tid = threadIdx.x;
    int wave = tid >> 6, lane = tid & 63;
    int b = blockIdx.z, h = blockIdx.y, n0 = blockIdx.x * 256;
    float th = thr[0];
    int cbase = h * 96;
    const float* xb = x + (size_t)b * C * N + n0 + lane * 4;
    const float* ib = inp + (size_t)b * C * N + n0 + lane * 4;
    float m0 = 0.f, m1 = 0.f, m2 = 0.f, m3 = 0.f;
    #pragma unroll
    for (int t = 0; t < 12; ++t) {
        int cp = wave * 12 + t;            // pair index 0..47 within half
        int c = cbase + cp * 2;
        float w0 = cm_w[c], w1 = cm_w[c + 1];
        float4 x0 = *(const float4*)&xb[(size_t)c * N];
        float4 x1 = *(const float4*)&xb[(size_t)(c + 1) * N];
        float4 i0 = *(const float4*)&ib[(size_t)c * N];
        float4 i1 = *(const float4*)&ib[(size_t)(c + 1) * N];
        m0 += (((i0.x - x0.x) > th) ? w0 : 0.f) + (((i1.x - x1.x) > th) ? w1 : 0.f);
        m1 += (((i0.y - x0.y) > th) ? w0 : 0.f) + (((i1.y - x1.y) > th) ? w1 : 0.f);
        m2 += (((i0.z - x0.z) > th) ? w0 : 0.f) + (((i1.z - x1.z) > th) ? w1 : 0.f);
        m3 += (((i0.w - x0.w) > th) ? w0 : 0.f) + (((i1.w - x1.w) > th) ? w1 : 0.f);
        ts[lane * 4 + 0][cp] = (unsigned int)f2bf(x0.x) | ((unsigned int)f2bf(x1.x) << 16);
        ts[lane * 4 + 1][cp] = (unsigned int)f2bf(x0.y) | ((unsigned int)f2bf(x1.y) << 16);
        ts[lane * 4 + 2][cp] = (unsigned int)f2bf(x0.z) | ((unsigned int)f2bf(x1.z) << 16);
        ts[lane * 4 + 3][cp] = (unsigned int)f2bf(x0.w) | ((unsigned int)f2bf(x1.w) << 16);
    }
    *(float4*)&partials[wave][lane * 4] = (float4){m0, m1, m2, m3};
    __syncthreads();
    // flush: thread t writes row t's half (96 ch = 192B contiguous)
    unsigned short* db = xt + ((size_t)b * N + n0 + tid) * C + cbase;
    #pragma unroll
    for (int q = 0; q < 12; ++q) {
        uint4 v;
        v.x = ts[tid][q * 4 + 0];
        v.y = ts[tid][q * 4 + 1];
        v.z = ts[tid][q * 4 + 2];
        v.w = ts[tid][q * 4 + 3];
        *(uint4*)&db[q * 8] = v;
    }
    float s = partials[0][tid] + partials[1][tid] + partials[2][tid] + partials[3][tid];
    atomicAdd(&mask_single[(size_t)b * N + n0 + tid], s);
}

// ---------------------------------------------------------------------------
// K3: qkv 1x1 conv via MFMA bf16: qkv_raw[b][o][n] = sum_c w[o][c]*x[b][c][n]
// ---------------------------------------------------------------------------
#define PAD 40
__global__ __launch_bounds__(256) void k_qkv_mfma(
    const unsigned short* __restrict__ xt, const float* __restrict__ w,
    unsigned short* __restrict__ out) {
    __shared__ __align__(16) unsigned short As[64][PAD];
    __shared__ __align__(16) unsigned short Bs[256][PAD];
    int b = blockIdx.z, m0 = blockIdx.y * 64, n0 = blockIdx.x * 256;
    int tid = threadIdx.x, wave = tid >> 6, lane = tid & 63;
    int l15 = lane & 15, quad = lane >> 4;
    floatx4 acc[4][4];
    #pragma unroll
    for (int i = 0; i < 4; ++i)
        #pragma unroll
        for (int j = 0; j < 4; ++j) acc[i][j] = (floatx4){0.f, 0.f, 0.f, 0.f};
    const unsigned short* xb = xt + (size_t)b * N * C;
    for (int k0 = 0; k0 < C; k0 += 32) {
        {
            int m = tid >> 2, ko = tid & 3;
            const float* wr = w + (size_t)(m0 + m) * C + k0 + ko * 8;
            float4 f0 = *(const float4*)&wr[0];
            float4 f1 = *(const float4*)&wr[4];
            unsigned int* dp = (unsigned int*)&As[m][ko * 8];
            dp[0] = (unsigned int)f2bf(f0.x) | ((unsigned int)f2bf(f0.y) << 16);
            dp[1] = (unsigned int)f2bf(f0.z) | ((unsigned int)f2bf(f0.w) << 16);
            dp[2] = (unsigned int)f2bf(f1.x) | ((unsigned int)f2bf(f1.y) << 16);
            dp[3] = (unsigned int)f2bf(f1.z) | ((unsigned int)f2bf(f1.w) << 16);
        }
        #pragma unroll
        for (int t = 0; t < 4; ++t) {
            int i = tid + t * 256;
            int n = i >> 2, ko = i & 3;
            *(uint4*)&Bs[n][ko * 8] = *(const uint4*)&xb[(size_t)(n0 + n) * C + k0 + ko * 8];
        }
        __syncthreads();
        short8 af[4], bf[4];
        #pragma unroll
        for (int mt = 0; mt < 4; ++mt)
            af[mt] = *(const short8*)&As[mt * 16 + l15][quad * 8];
        #pragma unroll
        for (int nt = 0; nt < 4; ++nt)
            bf[nt] = *(const short8*)&Bs[wave * 64 + nt * 16 + l15][quad * 8];
        #pragma unroll
        for (int mt = 0; mt < 4; ++mt)
            #pragma unroll
            for (int nt = 0; nt < 4; ++nt)
                acc[mt][nt] = __builtin_amdgcn_mfma_f32_16x16x32_bf16(
                    af[mt], bf[nt], acc[mt][nt], 0, 0, 0);
        __syncthreads();
    }
    unsigned short* ob = out + (size_t)b * OC * N;
    #pragma unroll
    for (int mt = 0; mt < 4; ++mt)
        #pragma unroll
        for (int r = 0; r < 4; ++r) {
            int o = m0 + mt * 16 + quad * 4 + r;
            #pragma unroll
            for (int nt = 0; nt < 4; ++nt)
                ob[(size_t)o * N + n0 + wave * 64 + nt * 16 + l15] =
                    f2bf(acc[mt][nt][r]);
        }
}

// ---------------------------------------------------------------------------
// K4: depthwise 3x3 (LDS-tiled) + mask + normsq.  v3:
//   - staging uint4 (8 bf16) per unit
//   - 2 output columns per thread, LDS tile [34][132]
// ---------------------------------------------------------------------------
__global__ __launch_bounds__(256) void k_dwconv(
    const unsigned short* __restrict__ qkv_raw, const float* __restrict__ dw_w,
    const float* __restrict__ mask_single, unsigned short* __restrict__ qk_out,
    unsigned short* __restrict__ v_out, float* __restrict__ normsq) {
    __shared__ float tile[34][132];
    __shared__ float red[4];
    int tid = threadIdx.x;
    int b = blockIdx.z, o = blockIdx.y;
    int y0 = blockIdx.x * 32;
    const unsigned short* in = qkv_raw + ((size_t)b * OC + o) * N;
    // staging: uint4 (8 bf16) per unit, 34 rows x 16 units
    for (int i = tid; i < 34 * 16; i += 256) {
        int r = i >> 4, dw = i & 15;
        int yy = y0 + r - 1;
        float4 f0 = {0.f, 0.f, 0.f, 0.f};
        float4 f1 = {0.f, 0.f, 0.f, 0.f};
        if (yy >= 0 && yy < H) {
            uint4 u = *(const uint4*)&in[yy * W + dw * 8];
            union { unsigned int i; float f; } a0, a1, a2, a3, a4, a5, a6, a7;
            a0.i = u.x << 16; a1.i = u.x & 0xffff0000u;
            a2.i = u.y << 16; a3.i = u.y & 0xffff0000u;
            a4.i = u.z << 16; a5.i = u.z & 0xffff0000u;
            a6.i = u.w << 16; a7.i = u.w & 0xffff0000u;
            f0.x = a0.f; f0.y = a1.f; f0.z = a2.f; f0.w = a3.f;
            f1.x = a4.f; f1.y = a5.f; f1.z = a6.f; f1.w = a7.f;
        }
        *(float4*)&tile[r][dw * 8] = f0;
        *(float4*)&tile[r][dw * 8 + 4] = f1;
        if (dw == 0)  { tile[r][130] = 0.f; tile[r][131] = 0.f; }
        if (dw == 15) { tile[r][128] = 0.f; }
    }
    __syncthreads();
    const float* wp = dw_w + o * 9;
    float w00 = wp[0], w01 = wp[1], w02 = wp[2];
    float w10 = wp[3], w11 = wp[4], w12 = wp[5];
    float w20 = wp[6], w21 = wp[7], w22 = wp[8];
    int c = tid & 63, g = tid >> 6;
    int col = c * 2;
    int lbase = (c == 0) ? 130 : (col - 2);   // .y of this pair = left neighbor
    bool is_qk = (o < 2 * C);
    float m_acc = 0.f;
    int rbase = g * 8;
    float2 p0l = *(const float2*)&tile[rbase][lbase];
    float2 p0m = *(const float2*)&tile[rbase][col];
    float2 p0r = *(const float2*)&tile[rbase][col + 2];
    float2 p1l = *(const float2*)&tile[rbase + 1][lbase];
    float2 p1m = *(const float2*)&tile[rbase + 1][col];
    float2 p1r = *(const float2*)&tile[rbase + 1][col + 2];
    unsigned short* qkb = qk_out + ((size_t)b * 2 * C + o) * N;
    unsigned short* vb  = v_out + ((size_t)b * C + (o - 2 * C)) * N;
    const float* mb = mask_single + (size_t)b * N;
    #pragma unroll
    for (int rl = 0; rl < 8; ++rl) {
        int tr = rbase + rl + 2;
        float2 p2l = *(const float2*)&tile[tr][lbase];
        float2 p2m = *(const float2*)&tile[tr][col];
        float2 p2r = *(const float2*)&tile[tr][col + 2];
        float sx = w00 * p0l.y + w01 * p0m.x + w02 * p0m.y
                 + w10 * p1l.y + w11 * p1m.x + w12 * p1m.y
                 + w20 * p2l.y + w21 * p2m.x + w22 * p2m.y;
        float sy = w00 * p0m.x + w01 * p0m.y + w02 * p0r.x
                 + w10 * p1m.x + w11 * p1m.y + w12 * p1r.x
                 + w20 * p2m.x + w21 * p2m.y + w22 * p2r.x;
        int p = (y0 + rbase + rl) * W + col;
        if (is_qk) {
            float2 mv = *(const float2*)&mb[p];
            sx *= mv.x; sy *= mv.y;
        }
        unsigned short hx = f2bf(sx), hy = f2bf(sy);
        unsigned int pk = (unsigned int)hx | ((unsigned int)hy << 16);
        if (is_qk) {
            *(unsigned int*)&qkb[p] = pk;
            float fx = bf2f(hx), fy = bf2f(hy);
            m_acc += fx * fx + fy * fy;
        } else {
            *(unsigned int*)&vb[p] = pk;
        }
        p0l = p1l; p0m = p1m; p0r = p1r;
        p1l = p2l; p1m = p2m; p1r = p2r;
    }
    if (is_qk) {
        #pragma unroll
        for (int off = 32; off > 0; off >>= 1) m_acc += __shfl_down(m_acc, off);
        if ((tid & 63) == 0) red[tid >> 6] = m_acc;
        __syncthreads();
        if (tid == 0)
            atomicAdd(&normsq[b * 2 * C + o], red[0] + red[1] + red[2] + red[3]);
    }
}

// ---------------------------------------------------------------------------
// K5: transpose v bf16 [b][c][n] -> v_t [b][n][c]
// ---------------------------------------------------------------------------
__global__ __launch_bounds__(256) void k_xpose_v(
    const unsigned short* __restrict__ src, unsigned short* __restrict__ dst) {
    __shared__ unsigned short t[64][C + 2];
    int tid = threadIdx.x;
    int b = blockIdx.y, n0 = blockIdx.x * 64;
    const unsigned short* sb = src + (size_t)b * C * N;
    for (int i = tid; i < C * 32; i += 256) {
        int c = i >> 5, np = i & 31;
        unsigned int u = *(const unsigned int*)&sb[(size_t)c * N + n0 + np * 2];
        t[np * 2][c] = (unsigned short)(u & 0xffffu);
        t[np * 2 + 1][c] = (unsigned short)(u >> 16);
    }
    __syncthreads();
    unsigned short* db = dst + ((size_t)b * N + n0) * C;
    for (int i = tid; i < 64 * (C / 8); i += 256) {
        int nn = i / (C / 8), ch = i % (C / 8);
        union { unsigned short h[8]; uint4 u; } pk;
        #pragma unroll
        for (int j = 0; j < 8; ++j) pk.h[j] = t[nn][ch * 8 + j];
        *(uint4*)&db[(size_t)nn * C + ch * 8] = pk.u;
    }
}

// ---------------------------------------------------------------------------
// K6: Gram via MFMA: G[b][h][i][j] = sum_n q[i][n]*k[j][n].
// ---------------------------------------------------------------------------
__global__ __launch_bounds__(256) void k_gram_mfma(
    const unsigned short* __restrict__ qk, float* __restrict__ G) {
    __shared__ float Gs[4][CH][CH];
    int tid = threadIdx.x, wave = tid >> 6, lane = tid & 63;
    int l15 = lane & 15, quad = lane >> 4;
    int b = blockIdx.z, hh = blockIdx.y;
    int nb = blockIdx.x * 512 + wave * 128;
    const unsigned short* qb = qk + ((size_t)b * 2 * C + hh * CH) * N;
    const unsigned short* kb = qb + (size_t)C * N;
    floatx4 acc[3][3];
    #pragma unroll
    for (int i = 0; i < 3; ++i)
        #pragma unroll
        for (int j = 0; j < 3; ++j) acc[i][j] = (floatx4){0.f, 0.f, 0.f, 0.f};
    #pragma unroll
    for (int ks = 0; ks < 4; ++ks) {
        int n_off = nb + ks * 32 + quad * 8;
        short8 af[3], bf[3];
        #pragma unroll
        for (int it = 0; it < 3; ++it)
            af[it] = *(const short8*)&qb[(size_t)(it * 16 + l15) * N + n_off];
        #pragma unroll
        for (int jt = 0; jt < 3; ++jt)
            bf[jt] = *(const short8*)&kb[(size_t)(jt * 16 + l15) * N + n_off];
        #pragma unroll
        for (int it = 0; it < 3; ++it)
            #pragma unroll
            for (int jt = 0; jt < 3; ++jt)
                acc[it][jt] = __builtin_amdgcn_mfma_f32_16x16x32_bf16(
                    af[it], bf[jt], acc[it][jt], 0, 0, 0);
    }
    #pragma unroll
    for (int it = 0; it < 3; ++it)
        #pragma unroll
        for (int jt = 0; jt < 3; ++jt)
            #pragma unroll
            for (int r = 0; r < 4; ++r)
                Gs[wave][it * 16 + quad * 4 + r][jt * 16 + l15] = acc[it][jt][r];
    __syncthreads();
    float* Gb = G + (size_t)(b * HEADS + hh) * CH * CH;
    for (int idx = tid; idx < CH * CH; idx += 256) {
        int i = idx / CH, j = idx % CH;
        atomicAdd(&Gb[idx], Gs[0][i][j] + Gs[1][i][j] + Gs[2][i][j] + Gs[3][i][j]);
    }
}

// ---------------------------------------------------------------------------
// K7: softmax(G*temp/(|q||k|)) folded into proj -> W_eff bf16 [b][o][c]
// ---------------------------------------------------------------------------
__global__ __launch_bounds__(256) void k_attn_weff(
    const float* __restrict__ G, const float* __restrict__ normsq,
    const float* __restrict__ temperature, const float* __restrict__ proj_w,
    unsigned short* __restrict__ W_eff) {
    int b = blockIdx.x;
    int o_base = blockIdx.y * 32;
    __shared__ float attn[HEADS][CH][CH];
    __shared__ float inv_n[2 * C];
    int tid = threadIdx.x;
    for (int l = tid; l < 2 * C; l += 256)
        inv_n[l] = 1.0f / fmaxf(sqrtf(normsq[b * 2 * C + l]), 1e-12f);
    __syncthreads();
    if (tid < HEADS * CH) {
        int hh = tid / CH, i = tid % CH;
        float iq = inv_n[hh * CH + i] * temperature[hh];
        const float* Gr = G + ((size_t)(b * HEADS + hh) * CH + i) * CH;
        float mx = -1e30f;
        for (int j = 0; j < CH; ++j) {
            float l2 = Gr[j] * iq * inv_n[C + hh * CH + j];
            attn[hh][i][j] = l2;
            mx = fmaxf(mx, l2);
        }
        float sm = 0.0f;
        for (int j = 0; j < CH; ++j) {
            float e = expf(attn[hh][i][j] - mx);
            attn[hh][i][j] = e;
            sm += e;
        }
        float is = 1.0f / sm;
        for (int j = 0; j < CH; ++j) attn[hh][i][j] *= is;
    }
    __syncthreads();
    for (int idx = tid; idx < 32 * C; idx += 256) {
        int o = o_base + idx / C, cp = idx % C;
        int hh = cp / CH, j = cp % CH;
        const float* pw = proj_w + (size_t)o * C + hh * CH;
        float s = 0.0f;
        #pragma unroll 8
        for (int i = 0; i < CH; ++i) s += pw[i] * attn[hh][i][j];
        W_eff[((size_t)b * C + o) * C + cp] = f2bf(s);
    }
}

// ---------------------------------------------------------------------------
// K8: out = W_eff[b] (192x192) @ v_t^T -> fp32, MFMA. Tile 64m x 256n.
// ---------------------------------------------------------------------------
__global__ __launch_bounds__(256) void k_out_mfma(
    const unsigned short* __restrict__ vt, const unsigned short* __restrict__ W_eff,
    float* __restrict__ out) {
    __shared__ __align__(16) unsigned short As[64][PAD];
    __shared__ __align__(16) unsigned short Bs[256][PAD];
    int b = blockIdx.z, m0 = blockIdx.y * 64, n0 = blockIdx.x * 256;
    int tid = threadIdx.x, wave = tid >> 6, lane = tid & 63;
    int l15 = lane & 15, quad = lane >> 4;
    floatx4 acc[4][4];
    #pragma unroll
    for (int i = 0; i < 4; ++i)
        #pragma unroll
        for (int j = 0; j < 4; ++j) acc[i][j] = (floatx4){0.f, 0.f, 0.f, 0.f};
    const unsigned short* vb = vt + (size_t)b * N * C;
    const unsigned short* wb = W_eff + (size_t)b * C * C;
    for (int k0 = 0; k0 < C; k0 += 32) {
        {
            int m = tid >> 2, ko = tid & 3;
            *(uint4*)&As[m][ko * 8] = *(const uint4*)&wb[(size_t)(m0 + m) * C + k0 + ko * 8];
        }
        #pragma unroll
        for (int t = 0; t < 4; ++t) {
            int i = tid + t * 256;
            int n = i >> 2, ko = i & 3;
            *(uint4*)&Bs[n][ko * 8] = *(const uint4*)&vb[(size_t)(n0 + n) * C + k0 + ko * 8];
        }
        __syncthreads();
        short8 af[4], bf[4];
        #pragma unroll
        for (int mt = 0; mt < 4; ++mt)
            af[mt] = *(const short8*)&As[mt * 16 + l15][quad * 8];
        #pragma unroll
        for (int nt = 0; nt < 4; ++nt)
            bf[nt] = *(const short8*)&Bs[wave * 64 + nt * 16 + l15][quad * 8];
        #pragma unroll
        for (int mt = 0; mt < 4; ++mt)
            #pragma unroll
            for (int nt = 0; nt < 4; ++nt)
                acc[mt][nt] = __builtin_amdgcn_mfma_f32_16x16x32_bf16(
                    af[mt], bf[nt], acc[mt][nt], 0, 0, 0);
        __syncthreads();
    }
    float* ob = out + (size_t)b * C * N;
    #pragma unroll
    for (int mt = 0; mt < 4; ++mt)
        #pragma unroll
        for (int r = 0; r < 4; ++r) {
            int o = m0 + mt * 16 + quad * 4 + r;
            #pragma unroll
            for (int nt = 0; nt < 4; ++nt)
                ob[(size_t)o * N + n0 + wave * 64 + nt * 16 + l15] = acc[mt][nt][r];
        }
}

// ---------------------------------------------------------------------------
extern "C" void kernel_launch(void* const* d_in, const int* in_sizes, int n_in,
                              void* d_out, int out_size, void* d_ws, size_t ws_size,
                              hipStream_t stream) {
    const float* x           = (const float*)d_in[0];
    const float* inp         = (const float*)d_in[1];
    const float* qkv_w       = (const float*)d_in[2];
    const float* dw_w        = (const float*)d_in[3];
    const float* proj_w      = (const float*)d_in[4];
    const float* cm_w        = (const float*)d_in[5];
    const float* temperature = (const float*)d_in[6];
    const float* threshold   = (const float*)d_in[7];
    float* out = (float*)d_out;

    char* ws = (char*)d_ws;
    const size_t SZ_RAW = (size_t)B * OC * N * 2;      // 150,994,944
    const size_t SZ_QK  = (size_t)B * 2 * C * N * 2;   // 100,663,296
    const size_t SZ_XT  = (size_t)B * N * C * 2;       //  50,331,648
    unsigned short* qkv_raw = (unsigned short*)ws;
    unsigned short* v_t     = (unsigned short*)ws;                       // reuse
    unsigned short* qk      = (unsigned short*)(ws + SZ_RAW);
    unsigned short* xt      = (unsigned short*)(ws + SZ_RAW + SZ_QK);
    unsigned short* vbuf    = xt;                                        // reuse
    char* tail = ws + SZ_RAW + SZ_QK + SZ_XT;
    float* mask_single = (float*)tail;
    float* normsq = (float*)(tail + (size_t)B * N * 4);
    float* G = normsq + B * 2 * C;
    unsigned short* W_eff = (unsigned short*)(G + B * HEADS * CH * CH);

    k_zero<<<dim3((B * N + 255) / 256), 256, 0, stream>>>(normsq, G, mask_single);
    k_mask_xt<<<dim3(N / 256, 2, B), 256, 0, stream>>>(x, inp, cm_w, threshold, mask_single, xt);
    k_qkv_mfma<<<dim3(N / 256, OC / 64, B), 256, 0, stream>>>(xt, qkv_w, qkv_raw);
    k_dwconv<<<dim3(H / 32, OC, B), 256, 0, stream>>>(qkv_raw, dw_w, mask_single, qk, vbuf, normsq);
    k_xpose_v<<<dim3(N / 64, B), 256, 0, stream>>>(vbuf, v_t);
    k_gram_mfma<<<dim3(N / 512, HEADS, B), 256, 0, stream>>>(qk, G);
    k_attn_weff<<<dim3(B, 6), 256, 0, stream>>>(G, normsq, temperature, proj_w, W_eff);
    k_out_mfma<<<dim3(N / 256, C / 64, B), 256, 0, stream>>>(v_t, W_eff, out);
}